// Round 1
// baseline (3714.732 us; speedup 1.0000x reference)
//
#include <hip/hip_runtime.h>
#include <math.h>

// Sizes from the reference
#define SEQ   1024
#define DX    620      // EMB 300 + CHAR_ENC 128 + 3*POS_SZ 192
#define BIH   128
#define TLH   256
#define NTAGS 16

// ws layout (float offsets)
#define O_X      0
#define O_XGF    634880              // 1024*620
#define O_XGB    (O_XGF + 524288)    // 1024*512
#define O_XIOU   (O_XGB + 524288)
#define O_XF     (O_XIOU + 786432)   // 1024*768
#define O_LCNN   (O_XF + 262400)     // 1025*256
#define O_SCNN   (O_LCNN + 131072)   // 1024*128
#define O_PART   (O_SCNN + 262144)   // 1024*256
#define O_GCNN   (O_PART + 4096)     // 16*256
#define O_HF     (O_GCNN + 256)
#define O_HB     (O_HF + 131072)
#define O_TREEH  (O_HB + 131072)
#define O_IOUA   (O_TREEH + 262144)  // 1024*256
#define O_FCSUM  (O_IOUA + 787200)   // 1025*768
#define O_EMIS   (O_FCSUM + 262400)  // 1025*256
#define O_CNT    (O_EMIS + 16384)    // 1024*16
// total ~ 4.72M floats ~ 18.9 MB

__device__ __forceinline__ float sig_f(float x){ return 1.0f/(1.0f + __expf(-x)); }
__device__ __forceinline__ float tanh_f(float x){
  float ax = fabsf(x);
  float e  = __expf(-2.0f*ax);
  float t  = (1.0f - e)/(1.0f + e);
  return x < 0.0f ? -t : t;
}

// ---------------- embeddings + char conv ----------------
__global__ __launch_bounds__(128) void k_embed(
    const int* __restrict__ wi, const int* __restrict__ ci,
    const int* __restrict__ postag_in, const int* __restrict__ dep_in, const int* __restrict__ pos_in,
    const float* __restrict__ word_table, const float* __restrict__ char_table,
    const float* __restrict__ ccw, const float* __restrict__ ccb,
    const float* __restrict__ postag_table, const float* __restrict__ position_table,
    float* __restrict__ x)
{
  int s = blockIdx.x;
  int tid = threadIdx.x;
  __shared__ __align__(16) float ce[50][16];   // [ic][t]
  for (int idx = tid; idx < 800; idx += 128){
    int e = idx >> 4, t = idx & 15;
    ce[e][t] = char_table[ci[s*16 + t]*50 + e];
  }
  __syncthreads();
  float* xr = x + (size_t)s*DX;
  const float* wrow = word_table + (size_t)wi[s]*300;
  for (int d = tid; d < 300; d += 128) xr[d] = wrow[d];
  {
    int oc = tid; // 128
    const float* wp = ccw + oc*150;
    float acc[16];
    float b = ccb[oc];
    #pragma unroll
    for (int t=0;t<16;t++) acc[t] = b;
    for (int ic=0; ic<50; ic++){
      float w0 = wp[ic*3+0], w1 = wp[ic*3+1], w2 = wp[ic*3+2];
      float cv[16];
      float4 c0 = *(const float4*)&ce[ic][0];
      float4 c1 = *(const float4*)&ce[ic][4];
      float4 c2 = *(const float4*)&ce[ic][8];
      float4 c3 = *(const float4*)&ce[ic][12];
      cv[0]=c0.x;cv[1]=c0.y;cv[2]=c0.z;cv[3]=c0.w;
      cv[4]=c1.x;cv[5]=c1.y;cv[6]=c1.z;cv[7]=c1.w;
      cv[8]=c2.x;cv[9]=c2.y;cv[10]=c2.z;cv[11]=c2.w;
      cv[12]=c3.x;cv[13]=c3.y;cv[14]=c3.z;cv[15]=c3.w;
      #pragma unroll
      for (int t=0;t<16;t++){
        float a = cv[t]*w1;
        if (t > 0)  a += cv[t-1]*w0;
        if (t < 15) a += cv[t+1]*w2;
        acc[t] += a;
      }
    }
    float m = acc[0];
    #pragma unroll
    for (int t=1;t<16;t++) m = fmaxf(m, acc[t]);
    xr[300 + oc] = fmaxf(m, 0.0f);
  }
  if (tid < 64){
    int d = tid;
    xr[428 + d] = postag_table[postag_in[s]*64 + d];
    xr[492 + d] = position_table[pos_in[s]*64 + d];
    xr[556 + d] = position_table[dep_in[s]*64 + d];
  }
}

// ---------------- fp32 GEMM: C[1024][N] = A @ B + bias ----------------
// amode 0: A = x[1024][620] direct, B row-major [K][N]
// amode 1: A = im2row3(x) [1024][1860] (k = d*3+kk, row shift kk-1), B = w [N][K]
struct GemmArgs {
  const float* B[6];
  const float* bias[6];
  float*       C[6];
  int N[6]; int K[6]; int amode[6];
};

__global__ __launch_bounds__(256) void k_gemm(const float* __restrict__ x, GemmArgs ga)
{
  int z = blockIdx.z;
  int N = ga.N[z], K = ga.K[z], amode = ga.amode[z];
  int bn = blockIdx.x*64;
  if (bn >= N) return;
  int bm = blockIdx.y*64;
  const float* __restrict__ Bm = ga.B[z];
  __shared__ __align__(16) float As[20][64];
  __shared__ __align__(16) float Bs[20][64];
  int tid = threadIdx.x;
  int lane = tid & 63, kg = tid >> 6;     // kg 0..3, each loads 5 k
  int tx = tid & 15, ty = tid >> 4;       // 16x16, micro 4x4
  float acc[4][4] = {{0.f}};
  for (int k0 = 0; k0 < K; k0 += 20){
    #pragma unroll
    for (int kk=0; kk<5; kk++){
      int k = kg*5 + kk;
      float av;
      if (amode == 0){
        av = x[(size_t)(bm+lane)*DX + k0 + k];
      } else {
        int kc = k0 + k;
        int d  = kc/3;
        int sh = kc - d*3 - 1;
        int row = bm + lane + sh;
        av = (row >= 0 && row < SEQ) ? x[(size_t)row*DX + d] : 0.0f;
      }
      As[k][lane] = av;
      Bs[k][lane] = (amode==0) ? Bm[(size_t)(k0+k)*N + bn + lane]
                               : Bm[(size_t)(bn+lane)*K + k0 + k];
    }
    __syncthreads();
    #pragma unroll
    for (int k=0;k<20;k++){
      float4 a = *(const float4*)&As[k][ty<<2];
      float4 b = *(const float4*)&Bs[k][tx<<2];
      acc[0][0]+=a.x*b.x; acc[0][1]+=a.x*b.y; acc[0][2]+=a.x*b.z; acc[0][3]+=a.x*b.w;
      acc[1][0]+=a.y*b.x; acc[1][1]+=a.y*b.y; acc[1][2]+=a.y*b.z; acc[1][3]+=a.y*b.w;
      acc[2][0]+=a.z*b.x; acc[2][1]+=a.z*b.y; acc[2][2]+=a.z*b.z; acc[2][3]+=a.z*b.w;
      acc[3][0]+=a.w*b.x; acc[3][1]+=a.w*b.y; acc[3][2]+=a.w*b.z; acc[3][3]+=a.w*b.w;
    }
    __syncthreads();
  }
  const float* bias = ga.bias[z];
  float* C = ga.C[z];
  float4 bb;
  bb.x = bias[bn+(tx<<2)+0]; bb.y = bias[bn+(tx<<2)+1];
  bb.z = bias[bn+(tx<<2)+2]; bb.w = bias[bn+(tx<<2)+3];
  #pragma unroll
  for (int i=0;i<4;i++){
    int row = bm + (ty<<2) + i;
    float4 o;
    o.x = acc[i][0] + bb.x; o.y = acc[i][1] + bb.y;
    o.z = acc[i][2] + bb.z; o.w = acc[i][3] + bb.w;
    *(float4*)&C[(size_t)row*N + bn + (tx<<2)] = o;
  }
}

// ---------------- global max over tokens for sent conv ----------------
__global__ __launch_bounds__(256) void k_gmax1(const float* __restrict__ scnn, float* __restrict__ part){
  int b = blockIdx.x, c = threadIdx.x;
  float m = -3.0e38f;
  for (int s = b*64; s < b*64 + 64; s++) m = fmaxf(m, scnn[(size_t)s*256 + c]);
  part[b*256 + c] = m;
}
__global__ __launch_bounds__(256) void k_gmax2(const float* __restrict__ part, float* __restrict__ gcnn){
  int c = threadIdx.x;
  float m = -3.0e38f;
  for (int b=0; b<16; b++) m = fmaxf(m, part[b*256 + c]);
  gcnn[c] = m;
}

// ---------------- persistent recurrent kernel ----------------
// blocks 0..7: tree-LSTM (unit slice of 32 per block, weights in registers)
// block 8: forward LSTM, block 9: backward LSTM (Wh columns in registers)
__global__ __launch_bounds__(512, 2) void k_recur(
    const float* __restrict__ xg_f, const float* __restrict__ xg_b,
    const float* __restrict__ Wh_f, const float* __restrict__ Wh_b,
    const float* __restrict__ xiou, const float* __restrict__ xf,
    const float* __restrict__ Uiou, const float* __restrict__ Uf,
    const int* __restrict__ order, const int* __restrict__ parent,
    float* __restrict__ hf, float* __restrict__ hb,
    float* tree_h, float* iou_acc, float* fcsum, unsigned* cnt)
{
  int blk = blockIdx.x;
  int tid = threadIdx.x;

  if (blk >= 8){
    // ---------- BiLSTM (one direction per block) ----------
    const float* xg  = (blk == 8) ? xg_f : xg_b;
    const float* Wh  = (blk == 8) ? Wh_f : Wh_b;
    float* hout      = (blk == 8) ? hf : hb;
    __shared__ __align__(16) float lhl[BIH];
    __shared__ float lgl[4*BIH];
    __shared__ float lcst[BIH];
    float w[BIH];
    #pragma unroll
    for (int r=0;r<BIH;r++) w[r] = Wh[r*512 + tid];
    if (tid < BIH){ lhl[tid] = 0.f; lcst[tid] = 0.f; }
    __syncthreads();
    for (int st=0; st<SEQ; st++){
      int n = (blk == 8) ? st : (SEQ-1-st);
      float xgv = xg[(size_t)n*512 + tid];
      float a0 = 0.f, a1 = 0.f;
      #pragma unroll
      for (int rb=0; rb<BIH/4; rb++){
        float4 h4 = *(const float4*)&lhl[rb*4];
        a0 += h4.x*w[rb*4+0] + h4.z*w[rb*4+2];
        a1 += h4.y*w[rb*4+1] + h4.w*w[rb*4+3];
      }
      lgl[tid] = a0 + a1 + xgv;
      __syncthreads();
      if (tid < BIH){
        float gi = lgl[tid], gf = lgl[BIH+tid], gg = lgl[2*BIH+tid], go = lgl[3*BIH+tid];
        float c = sig_f(gf)*lcst[tid] + sig_f(gi)*tanh_f(gg);
        float h = sig_f(go)*tanh_f(c);
        lcst[tid] = c;
        lhl[tid] = h;
        hout[(size_t)n*BIH + tid] = h;
      }
      __syncthreads();
    }
    return;
  }

  // ---------- tree-LSTM ----------
  int q = tid >> 7;     // row quarter 0..3
  int c = tid & 127;    // column within slice: 0..95 iou, 96..127 f
  float w[64];
  if (c < 96){
    int gcol = (c>>5)*TLH + blk*32 + (c&31);   // gates i,o,u at col offsets 0,256,512
    #pragma unroll
    for (int r=0;r<64;r++) w[r] = Uiou[(size_t)(q*64+r)*768 + gcol];
  } else {
    int fcol = blk*32 + (c-96);
    #pragma unroll
    for (int r=0;r<64;r++) w[r] = Uf[(size_t)(q*64+r)*256 + fcol];
  }
  __shared__ __align__(16) float hl[TLH];
  __shared__ float part[128][5];
  __shared__ float cprev[32];
  __shared__ float passv[128];
  __shared__ int ord_l[SEQ];
  __shared__ int par_l[SEQ];
  for (int i=tid; i<SEQ; i+=512){ ord_l[i] = order[i]; par_l[i] = parent[i]; }
  __syncthreads();

  for (int t=0; t<SEQ; t++){
    int n = ord_l[t];
    bool ppeq = false;
    // prefetch xiou row for phase B (hidden under matvec)
    float xi=0.f, xo=0.f, xu=0.f;
    if (tid < 32){
      int u = blk*32 + tid;
      xi = xiou[(size_t)n*768 + u];
      xo = xiou[(size_t)n*768 + 256 + u];
      xu = xiou[(size_t)n*768 + 512 + u];
    }
    if (t > 0){
      int m  = ord_l[t-1];
      int pp = par_l[m];
      ppeq = (pp == n);
      // prefetch accumulator olds early (latency hidden by matvec)
      float oldv = 0.f, xfv = 0.f;
      if (tid < 96){
        oldv = iou_acc[(size_t)pp*768 + (tid>>5)*TLH + blk*32 + (tid&31)];
      } else if (tid < 128){
        int fc = blk*32 + (tid-96);
        oldv = fcsum[(size_t)pp*256 + fc];
        xfv  = xf[(size_t)pp*256 + fc];
      }
      // matvec with h of previously-processed node
      float a0 = 0.f, a1 = 0.f;
      #pragma unroll
      for (int rb=0; rb<16; rb++){
        float4 h4 = *(const float4*)&hl[q*64 + rb*4];
        a0 += h4.x*w[rb*4+0] + h4.z*w[rb*4+2];
        a1 += h4.y*w[rb*4+1] + h4.w*w[rb*4+3];
      }
      part[c][q] = a0 + a1;
      __syncthreads();
      if (tid < 128){
        float v = part[tid][0] + part[tid][1] + part[tid][2] + part[tid][3];
        if (tid < 96){
          float tot = oldv + v;
          iou_acc[(size_t)pp*768 + (tid>>5)*TLH + blk*32 + (tid&31)] = tot;
          passv[tid] = tot;
        } else {
          float fg = sig_f(xfv + v);
          float tot = oldv + fg * cprev[tid-96];
          fcsum[(size_t)pp*256 + blk*32 + (tid-96)] = tot;
          passv[tid] = tot;
        }
      }
      __syncthreads();
    }
    // phase B: finish node n for our unit slice
    if (tid < 32){
      int u = blk*32 + tid;
      float ai, ao, au, fcs;
      if (ppeq){
        ai = passv[tid]; ao = passv[32+tid]; au = passv[64+tid]; fcs = passv[96+tid];
      } else {
        ai = iou_acc[(size_t)n*768 + u];
        ao = iou_acc[(size_t)n*768 + 256 + u];
        au = iou_acc[(size_t)n*768 + 512 + u];
        fcs = fcsum[(size_t)n*256 + u];
      }
      float cc = sig_f(xi + ai)*tanh_f(xu + au) + fcs;
      float hh = sig_f(xo + ao)*tanh_f(cc);
      cprev[tid] = cc;
      __hip_atomic_store(&tree_h[(size_t)n*TLH + u], hh, __ATOMIC_RELEASE, __HIP_MEMORY_SCOPE_AGENT);
    }
    __syncthreads();
    if (tid == 0){
      __hip_atomic_fetch_add(cnt, 1u, __ATOMIC_ACQ_REL, __HIP_MEMORY_SCOPE_AGENT);
      unsigned tgt = 8u*(unsigned)(t+1);
      while (__hip_atomic_load(cnt, __ATOMIC_ACQUIRE, __HIP_MEMORY_SCOPE_AGENT) < tgt){
        __builtin_amdgcn_s_sleep(4);
      }
    }
    __syncthreads();
    if (tid < TLH)
      hl[tid] = __hip_atomic_load(&tree_h[(size_t)n*TLH + tid], __ATOMIC_RELAXED, __HIP_MEMORY_SCOPE_AGENT);
    __syncthreads();
  }
}

// ---------------- assemble SE + emissions + relations ----------------
__global__ __launch_bounds__(256) void k_assemble(
    const float* __restrict__ hf, const float* __restrict__ hb,
    const float* __restrict__ lcnn, const float* __restrict__ tree_h,
    const float* __restrict__ gcnn,
    const float* __restrict__ crf_w, const float* __restrict__ crf_b,
    const float* __restrict__ rel_w, const float* __restrict__ rel_b,
    const int* __restrict__ ptk,
    float* __restrict__ se_out, float* __restrict__ emis, float* __restrict__ rel_out)
{
  int s = blockIdx.x, tid = threadIdx.x;
  int p = ptk[0];
  __shared__ float se[1536];
  for (int d = tid; d < 1536; d += 256){
    float v;
    if      (d < 128)  v = hf[(size_t)s*128 + d];
    else if (d < 256)  v = hb[(size_t)s*128 + d-128];
    else if (d < 384)  v = lcnn[(size_t)s*128 + d-256];
    else if (d < 640)  v = tree_h[(size_t)s*256 + d-384];
    else if (d < 768)  v = hf[(size_t)p*128 + d-640];
    else if (d < 896)  v = hb[(size_t)p*128 + d-768];
    else if (d < 1024) v = lcnn[(size_t)p*128 + d-896];
    else if (d < 1280) v = tree_h[(size_t)p*256 + d-1024];
    else               v = gcnn[d-1280];
    se[d] = v;
    se_out[(size_t)s*1536 + d] = v;
  }
  __syncthreads();
  int o = tid >> 3, l = tid & 7;   // 32 outputs x 8 lanes
  const float* W = (o < 16) ? crf_w : rel_w;
  int oc = (o < 16) ? o : (o - 16);
  float a = 0.f;
  for (int k = l; k < 1536; k += 8) a += se[k]*W[(size_t)k*16 + oc];
  for (int off = 4; off; off >>= 1) a += __shfl_down(a, off, 8);
  if (l == 0){
    if (o < 16) emis[(size_t)s*16 + o] = a + crf_b[o];
    else        rel_out[(size_t)s*16 + oc] = sig_f(a + rel_b[oc]);
  }
}

// ---------------- entity type (softmax of one_vec @ et_w + b) ----------------
__global__ __launch_bounds__(256) void k_entity(
    const float* __restrict__ hf, const float* __restrict__ hb,
    const float* __restrict__ lcnn, const float* __restrict__ tree_h,
    const float* __restrict__ gcnn,
    const float* __restrict__ et_w, const float* __restrict__ et_b,
    const int* __restrict__ ptk, float* __restrict__ out_et)
{
  __shared__ float ov[896];
  __shared__ float lg[8];
  int tid = threadIdx.x;
  int p = ptk[0];
  for (int d = tid; d < 896; d += 256){
    float v;
    if      (d < 256) v = gcnn[d];
    else if (d < 384) v = hf[(size_t)p*128 + d-256];
    else if (d < 512) v = hb[(size_t)p*128 + d-384];
    else if (d < 640) v = lcnn[(size_t)p*128 + d-512];
    else              v = tree_h[(size_t)p*256 + d-640];
    ov[d] = v;
  }
  __syncthreads();
  int o = tid >> 5, l = tid & 31;
  float a = 0.f;
  for (int k = l; k < 896; k += 32) a += ov[k]*et_w[(size_t)k*8 + o];
  for (int off = 16; off; off >>= 1) a += __shfl_down(a, off, 32);
  if (l == 0) lg[o] = a + et_b[o];
  __syncthreads();
  if (tid == 0){
    float mx = lg[0];
    for (int i=1;i<8;i++) mx = fmaxf(mx, lg[i]);
    float e[8], sum = 0.f;
    for (int i=0;i<8;i++){ e[i] = __expf(lg[i]-mx); sum += e[i]; }
    for (int i=0;i<8;i++) out_et[i] = e[i]/sum;
  }
}

// ---------------- viterbi (wave0 computes, wave1 prefetches emissions) ----------------
__global__ __launch_bounds__(128) void k_viterbi(
    const float* __restrict__ emis, const float* __restrict__ trans, float* __restrict__ out_e)
{
  __shared__ float ring[64][16];
  __shared__ float sc[16], nsc[16];
  __shared__ float tr[256];
  __shared__ unsigned char ptrs[1023*16];
  int tid = threadIdx.x;
  for (int i=tid; i<256; i+=128) tr[i] = trans[i];
  for (int i=tid; i<33*16; i+=128) ring[i>>4][i&15] = emis[i];   // rows 0..32
  if (tid < 16) sc[tid] = emis[tid];
  __syncthreads();
  int j = (tid & 63) >> 2, iq = tid & 3;
  for (int t=1; t<1024; t++){
    if (tid >= 64){
      int lr = tid - 64;
      int tl = t + 32;
      if (lr < 16 && tl < 1024) ring[tl & 63][lr] = emis[(size_t)tl*16 + lr];
    } else {
      float best = -3.0e38f; int barg = 0;
      #pragma unroll
      for (int ii=0; ii<4; ii++){
        int i = iq*4 + ii;
        float v = sc[i] + tr[i*16 + j];
        if (v > best){ best = v; barg = i; }   // strict > keeps first max
      }
      #pragma unroll
      for (int off=1; off<4; off<<=1){
        float ovv = __shfl_down(best, off, 4);
        int   oaa = __shfl_down(barg, off, 4);
        if (ovv > best){ best = ovv; barg = oaa; }  // neighbor has larger index: > keeps first
      }
      if (iq == 0){
        nsc[j] = best + ring[t & 63][j];
        ptrs[(t-1)*16 + j] = (unsigned char)barg;
      }
    }
    __syncthreads();
    if (tid < 16) sc[tid] = nsc[tid];
    __syncthreads();
  }
  if (tid == 0){
    float b = sc[0]; int last = 0;
    #pragma unroll
    for (int i=1;i<16;i++){ if (sc[i] > b){ b = sc[i]; last = i; } }
    out_e[1023] = (float)last;
    int cur = last;
    for (int t=1022; t>=0; t--){ cur = (int)ptrs[t*16 + cur]; out_e[t] = (float)cur; }
  }
}

extern "C" void kernel_launch(void* const* d_in, const int* in_sizes, int n_in,
                              void* d_out, int out_size, void* d_ws, size_t ws_size,
                              hipStream_t stream)
{
  (void)in_sizes; (void)n_in; (void)out_size; (void)ws_size;
  const int*   wi         = (const int*)d_in[0];
  const int*   ci         = (const int*)d_in[1];
  const int*   postag_in  = (const int*)d_in[2];
  const int*   dep_in     = (const int*)d_in[3];
  const int*   pos_in     = (const int*)d_in[4];
  const int*   order      = (const int*)d_in[5];
  const int*   parent     = (const int*)d_in[6];
  const int*   ptk        = (const int*)d_in[7];
  const float* word_table = (const float*)d_in[8];
  const float* char_table = (const float*)d_in[9];
  const float* ccw        = (const float*)d_in[10];
  const float* ccb        = (const float*)d_in[11];
  const float* postag_tab = (const float*)d_in[12];
  const float* pos_tab    = (const float*)d_in[13];
  const float* Wx_f       = (const float*)d_in[14];
  const float* Wh_f       = (const float*)d_in[15];
  const float* b_f        = (const float*)d_in[16];
  const float* Wx_b       = (const float*)d_in[17];
  const float* Wh_b       = (const float*)d_in[18];
  const float* b_b        = (const float*)d_in[19];
  const float* wcnn_w     = (const float*)d_in[20];
  const float* wcnn_b     = (const float*)d_in[21];
  const float* Wiou       = (const float*)d_in[22];
  const float* Uiou       = (const float*)d_in[23];
  const float* biou       = (const float*)d_in[24];
  const float* Wf_t       = (const float*)d_in[25];
  const float* Uf_t       = (const float*)d_in[26];
  const float* bf_t       = (const float*)d_in[27];
  const float* scnn_w     = (const float*)d_in[28];
  const float* scnn_b     = (const float*)d_in[29];
  const float* et_w       = (const float*)d_in[30];
  const float* et_b       = (const float*)d_in[31];
  const float* crf_w      = (const float*)d_in[32];
  const float* crf_b      = (const float*)d_in[33];
  const float* crf_trans  = (const float*)d_in[34];
  const float* rel_w      = (const float*)d_in[35];
  const float* rel_b      = (const float*)d_in[36];

  float* ws = (float*)d_ws;
  float* x      = ws + O_X;
  float* xg_f   = ws + O_XGF;
  float* xg_b   = ws + O_XGB;
  float* xiou   = ws + O_XIOU;
  float* xf     = ws + O_XF;
  float* lcnn   = ws + O_LCNN;
  float* scnn   = ws + O_SCNN;
  float* part   = ws + O_PART;
  float* gcnn   = ws + O_GCNN;
  float* hf     = ws + O_HF;
  float* hb     = ws + O_HB;
  float* tree_h = ws + O_TREEH;
  float* iou_acc= ws + O_IOUA;
  float* fcsum  = ws + O_FCSUM;
  float* emis   = ws + O_EMIS;
  unsigned* cnt = (unsigned*)(ws + O_CNT);

  float* outF     = (float*)d_out;
  float* se_out   = outF;                       // 1024*1536
  float* et_out   = outF + 1572864;             // 8
  float* ent_out  = outF + 1572872;             // 1024
  float* rel_out  = outF + 1573896;             // 1024*16

  // zero the accumulators / xf pad row / barrier counter (required every launch)
  hipMemsetAsync(xf, 0, (size_t)1025*256*sizeof(float), stream);
  hipMemsetAsync(iou_acc, 0, ((size_t)1025*768 + 1025*256)*sizeof(float), stream);
  hipMemsetAsync(cnt, 0, 64, stream);

  k_embed<<<SEQ, 128, 0, stream>>>(wi, ci, postag_in, dep_in, pos_in,
                                   word_table, char_table, ccw, ccb,
                                   postag_tab, pos_tab, x);

  GemmArgs ga;
  ga.B[0]=Wx_f;  ga.bias[0]=b_f;   ga.C[0]=xg_f; ga.N[0]=512; ga.K[0]=620;  ga.amode[0]=0;
  ga.B[1]=Wx_b;  ga.bias[1]=b_b;   ga.C[1]=xg_b; ga.N[1]=512; ga.K[1]=620;  ga.amode[1]=0;
  ga.B[2]=Wiou;  ga.bias[2]=biou;  ga.C[2]=xiou; ga.N[2]=768; ga.K[2]=620;  ga.amode[2]=0;
  ga.B[3]=Wf_t;  ga.bias[3]=bf_t;  ga.C[3]=xf;   ga.N[3]=256; ga.K[3]=620;  ga.amode[3]=0;
  ga.B[4]=wcnn_w;ga.bias[4]=wcnn_b;ga.C[4]=lcnn; ga.N[4]=128; ga.K[4]=1860; ga.amode[4]=1;
  ga.B[5]=scnn_w;ga.bias[5]=scnn_b;ga.C[5]=scnn; ga.N[5]=256; ga.K[5]=1860; ga.amode[5]=1;
  k_gemm<<<dim3(12,16,6), 256, 0, stream>>>(x, ga);

  k_gmax1<<<16, 256, 0, stream>>>(scnn, part);
  k_gmax2<<<1, 256, 0, stream>>>(part, gcnn);

  k_recur<<<10, 512, 0, stream>>>(xg_f, xg_b, Wh_f, Wh_b, xiou, xf, Uiou, Uf_t,
                                  order, parent, hf, hb, tree_h, iou_acc, fcsum, cnt);

  k_assemble<<<SEQ, 256, 0, stream>>>(hf, hb, lcnn, tree_h, gcnn,
                                      crf_w, crf_b, rel_w, rel_b, ptk,
                                      se_out, emis, rel_out);

  k_entity<<<1, 256, 0, stream>>>(hf, hb, lcnn, tree_h, gcnn, et_w, et_b, ptk, et_out);

  k_viterbi<<<1, 128, 0, stream>>>(emis, crf_trans, ent_out);
}

// Round 2
// 2912.401 us; speedup vs baseline: 1.2755x; 1.2755x over previous
//
#include <hip/hip_runtime.h>
#include <math.h>

// Sizes from the reference
#define SEQ   1024
#define DX    620      // EMB 300 + CHAR_ENC 128 + 3*POS_SZ 192
#define BIH   128
#define TLH   256
#define NTAGS 16

// ws layout (float offsets)
#define O_X      0
#define O_XGF    634880              // 1024*620
#define O_XGB    (O_XGF + 524288)    // 1024*512
#define O_XIOU   (O_XGB + 524288)
#define O_XF     (O_XIOU + 786432)   // 1024*768
#define O_LCNN   (O_XF + 262400)     // 1025*256
#define O_SCNN   (O_LCNN + 131072)   // 1024*128
#define O_PART   (O_SCNN + 262144)   // 1024*256
#define O_GCNN   (O_PART + 4096)     // 16*256
#define O_HF     (O_GCNN + 256)
#define O_HB     (O_HF + 131072)
#define O_TREEH  (O_HB + 131072)
#define O_IOUA   (O_TREEH + 262144)  // 1024*256
#define O_FCSUM  (O_IOUA + 787200)   // 1025*768
#define O_EMIS   (O_FCSUM + 262400)  // 1025*256
#define O_CNT    (O_EMIS + 16384)    // 1024*16

#define SENT 0xFFFFFFFFu

__device__ __forceinline__ float sig_f(float x){ return 1.0f/(1.0f + __expf(-x)); }
__device__ __forceinline__ float tanh_f(float x){
  float ax = fabsf(x);
  float e  = __expf(-2.0f*ax);
  float t  = (1.0f - e)/(1.0f + e);
  return x < 0.0f ? -t : t;
}

// ---------------- embeddings + char conv ----------------
__global__ __launch_bounds__(128) void k_embed(
    const int* __restrict__ wi, const int* __restrict__ ci,
    const int* __restrict__ postag_in, const int* __restrict__ dep_in, const int* __restrict__ pos_in,
    const float* __restrict__ word_table, const float* __restrict__ char_table,
    const float* __restrict__ ccw, const float* __restrict__ ccb,
    const float* __restrict__ postag_table, const float* __restrict__ position_table,
    float* __restrict__ x)
{
  int s = blockIdx.x;
  int tid = threadIdx.x;
  __shared__ __align__(16) float ce[50][16];   // [ic][t]
  for (int idx = tid; idx < 800; idx += 128){
    int e = idx >> 4, t = idx & 15;
    ce[e][t] = char_table[ci[s*16 + t]*50 + e];
  }
  __syncthreads();
  float* xr = x + (size_t)s*DX;
  const float* wrow = word_table + (size_t)wi[s]*300;
  for (int d = tid; d < 300; d += 128) xr[d] = wrow[d];
  {
    int oc = tid; // 128
    const float* wp = ccw + oc*150;
    float acc[16];
    float b = ccb[oc];
    #pragma unroll
    for (int t=0;t<16;t++) acc[t] = b;
    for (int ic=0; ic<50; ic++){
      float w0 = wp[ic*3+0], w1 = wp[ic*3+1], w2 = wp[ic*3+2];
      float cv[16];
      float4 c0 = *(const float4*)&ce[ic][0];
      float4 c1 = *(const float4*)&ce[ic][4];
      float4 c2 = *(const float4*)&ce[ic][8];
      float4 c3 = *(const float4*)&ce[ic][12];
      cv[0]=c0.x;cv[1]=c0.y;cv[2]=c0.z;cv[3]=c0.w;
      cv[4]=c1.x;cv[5]=c1.y;cv[6]=c1.z;cv[7]=c1.w;
      cv[8]=c2.x;cv[9]=c2.y;cv[10]=c2.z;cv[11]=c2.w;
      cv[12]=c3.x;cv[13]=c3.y;cv[14]=c3.z;cv[15]=c3.w;
      #pragma unroll
      for (int t=0;t<16;t++){
        float a = cv[t]*w1;
        if (t > 0)  a += cv[t-1]*w0;
        if (t < 15) a += cv[t+1]*w2;
        acc[t] += a;
      }
    }
    float m = acc[0];
    #pragma unroll
    for (int t=1;t<16;t++) m = fmaxf(m, acc[t]);
    xr[300 + oc] = fmaxf(m, 0.0f);
  }
  if (tid < 64){
    int d = tid;
    xr[428 + d] = postag_table[postag_in[s]*64 + d];
    xr[492 + d] = position_table[pos_in[s]*64 + d];
    xr[556 + d] = position_table[dep_in[s]*64 + d];
  }
}

// ---------------- fp32 GEMM: C[1024][N] = A @ B + bias ----------------
struct GemmArgs {
  const float* B[6];
  const float* bias[6];
  float*       C[6];
  int N[6]; int K[6]; int amode[6];
};

__global__ __launch_bounds__(256) void k_gemm(const float* __restrict__ x, GemmArgs ga)
{
  int z = blockIdx.z;
  int N = ga.N[z], K = ga.K[z], amode = ga.amode[z];
  int bn = blockIdx.x*64;
  if (bn >= N) return;
  int bm = blockIdx.y*64;
  const float* __restrict__ Bm = ga.B[z];
  __shared__ __align__(16) float As[20][64];
  __shared__ __align__(16) float Bs[20][64];
  int tid = threadIdx.x;
  int lane = tid & 63, kg = tid >> 6;     // kg 0..3, each loads 5 k
  int tx = tid & 15, ty = tid >> 4;       // 16x16, micro 4x4
  float acc[4][4] = {{0.f}};
  for (int k0 = 0; k0 < K; k0 += 20){
    #pragma unroll
    for (int kk=0; kk<5; kk++){
      int k = kg*5 + kk;
      float av;
      if (amode == 0){
        av = x[(size_t)(bm+lane)*DX + k0 + k];
      } else {
        int kc = k0 + k;
        int d  = kc/3;
        int sh = kc - d*3 - 1;
        int row = bm + lane + sh;
        av = (row >= 0 && row < SEQ) ? x[(size_t)row*DX + d] : 0.0f;
      }
      As[k][lane] = av;
      Bs[k][lane] = (amode==0) ? Bm[(size_t)(k0+k)*N + bn + lane]
                               : Bm[(size_t)(bn+lane)*K + k0 + k];
    }
    __syncthreads();
    #pragma unroll
    for (int k=0;k<20;k++){
      float4 a = *(const float4*)&As[k][ty<<2];
      float4 b = *(const float4*)&Bs[k][tx<<2];
      acc[0][0]+=a.x*b.x; acc[0][1]+=a.x*b.y; acc[0][2]+=a.x*b.z; acc[0][3]+=a.x*b.w;
      acc[1][0]+=a.y*b.x; acc[1][1]+=a.y*b.y; acc[1][2]+=a.y*b.z; acc[1][3]+=a.y*b.w;
      acc[2][0]+=a.z*b.x; acc[2][1]+=a.z*b.y; acc[2][2]+=a.z*b.z; acc[2][3]+=a.z*b.w;
      acc[3][0]+=a.w*b.x; acc[3][1]+=a.w*b.y; acc[3][2]+=a.w*b.z; acc[3][3]+=a.w*b.w;
    }
    __syncthreads();
  }
  const float* bias = ga.bias[z];
  float* C = ga.C[z];
  float4 bb;
  bb.x = bias[bn+(tx<<2)+0]; bb.y = bias[bn+(tx<<2)+1];
  bb.z = bias[bn+(tx<<2)+2]; bb.w = bias[bn+(tx<<2)+3];
  #pragma unroll
  for (int i=0;i<4;i++){
    int row = bm + (ty<<2) + i;
    float4 o;
    o.x = acc[i][0] + bb.x; o.y = acc[i][1] + bb.y;
    o.z = acc[i][2] + bb.z; o.w = acc[i][3] + bb.w;
    *(float4*)&C[(size_t)row*N + bn + (tx<<2)] = o;
  }
}

// ---------------- global max over tokens for sent conv (fused) ----------------
__global__ __launch_bounds__(256) void k_gmax(const float* __restrict__ scnn, float* __restrict__ gcnn){
  int c = threadIdx.x;
  float m = -3.0e38f;
  #pragma unroll 8
  for (int s = 0; s < SEQ; s++) m = fmaxf(m, scnn[(size_t)s*256 + c]);
  gcnn[c] = m;
}

// ---------------- persistent recurrent kernel ----------------
// blocks 0..3: tree-LSTM (64-unit slice per block, weights in registers)
// block 4: forward LSTM, block 5: backward LSTM
// Tree sync is pure dataflow: tree_h pre-filled with 0xFFFFFFFF sentinel;
// producers store finished h (relaxed, agent scope); consumers poll data bits.
__global__ __launch_bounds__(1024) void k_recur(
    const float* __restrict__ xg_f, const float* __restrict__ xg_b,
    const float* __restrict__ Wh_f, const float* __restrict__ Wh_b,
    const float* __restrict__ xiou, const float* __restrict__ xf,
    const float* __restrict__ Uiou, const float* __restrict__ Uf,
    const int* __restrict__ order, const int* __restrict__ parent,
    float* __restrict__ hf, float* __restrict__ hb,
    float* tree_h, float* iou_acc, float* fcsum)
{
  int blk = blockIdx.x;
  int tid = threadIdx.x;

  if (blk >= 4){
    // ---------- BiLSTM: 2 threads per gate-column, 64 rows each ----------
    const float* xg  = (blk == 4) ? xg_f : xg_b;
    const float* Wh  = (blk == 4) ? Wh_f : Wh_b;
    float* hout      = (blk == 4) ? hf : hb;
    int col = tid & 511, half = tid >> 9;
    float4 w4[16];
    #pragma unroll
    for (int r=0;r<16;r++){
      w4[r].x = Wh[(size_t)(half*64 + r*4+0)*512 + col];
      w4[r].y = Wh[(size_t)(half*64 + r*4+1)*512 + col];
      w4[r].z = Wh[(size_t)(half*64 + r*4+2)*512 + col];
      w4[r].w = Wh[(size_t)(half*64 + r*4+3)*512 + col];
    }
    __shared__ __align__(16) float lhl[BIH];
    __shared__ float lcst[BIH];
    __shared__ float pr[512];
    __shared__ float gl[512];
    if (tid < BIH){ lhl[tid] = 0.f; lcst[tid] = 0.f; }
    __syncthreads();
    for (int st=0; st<SEQ; st++){
      int n = (blk == 4) ? st : (SEQ-1-st);
      float xgv = (half == 0) ? xg[(size_t)n*512 + col] : 0.f;
      float a = 0.f;
      #pragma unroll
      for (int r=0;r<16;r++){
        float4 h4 = *(const float4*)&lhl[half*64 + r*4];
        a += h4.x*w4[r].x + h4.y*w4[r].y + h4.z*w4[r].z + h4.w*w4[r].w;
      }
      if (half) pr[col] = a;
      __syncthreads();
      if (!half) gl[col] = a + pr[col] + xgv;
      __syncthreads();
      if (tid < BIH){
        float gi = gl[tid], gf = gl[BIH+tid], gg = gl[2*BIH+tid], go = gl[3*BIH+tid];
        float c = sig_f(gf)*lcst[tid] + sig_f(gi)*tanh_f(gg);
        float h = sig_f(go)*tanh_f(c);
        lcst[tid] = c;
        lhl[tid] = h;
        hout[(size_t)n*BIH + tid] = h;
      }
      __syncthreads();
    }
    return;
  }

  // ---------- tree-LSTM: 64 units per block ----------
  int q = tid >> 8;     // row quarter 0..3 (64 rows each)
  int c = tid & 255;    // col: 0..191 iou (g=c>>6), 192..255 f
  float4 w4[16];
  if (c < 192){
    int gcol = (c>>6)*TLH + blk*64 + (c&63);
    #pragma unroll
    for (int r=0;r<16;r++){
      w4[r].x = Uiou[(size_t)(q*64 + r*4+0)*768 + gcol];
      w4[r].y = Uiou[(size_t)(q*64 + r*4+1)*768 + gcol];
      w4[r].z = Uiou[(size_t)(q*64 + r*4+2)*768 + gcol];
      w4[r].w = Uiou[(size_t)(q*64 + r*4+3)*768 + gcol];
    }
  } else {
    int fcol = blk*64 + (c-192);
    #pragma unroll
    for (int r=0;r<16;r++){
      w4[r].x = Uf[(size_t)(q*64 + r*4+0)*256 + fcol];
      w4[r].y = Uf[(size_t)(q*64 + r*4+1)*256 + fcol];
      w4[r].z = Uf[(size_t)(q*64 + r*4+2)*256 + fcol];
      w4[r].w = Uf[(size_t)(q*64 + r*4+3)*256 + fcol];
    }
  }
  __shared__ __align__(16) float hl[TLH];
  __shared__ float part[256][5];
  __shared__ float cprev[64];
  __shared__ float passv[256];
  __shared__ int ord_l[SEQ];
  __shared__ int par_l[SEQ];
  for (int i=tid; i<SEQ; i+=1024){ ord_l[i] = order[i]; par_l[i] = parent[i]; }
  int ulo = blk*64, uhi = blk*64 + 64;
  __syncthreads();

  for (int t=0; t<SEQ; t++){
    int n = ord_l[t];
    bool ppeq = false;
    // prefetch xiou row for phase B (hidden under matvec)
    float xi=0.f, xo=0.f, xu=0.f;
    if (tid < 64){
      int u = ulo + tid;
      xi = xiou[(size_t)n*768 + u];
      xo = xiou[(size_t)n*768 + 256 + u];
      xu = xiou[(size_t)n*768 + 512 + u];
    }
    if (t > 0){
      int m  = ord_l[t-1];
      int pp = par_l[m];
      ppeq = (pp == n);
      // prefetch accumulator olds early (latency hidden by matvec)
      float oldv = 0.f, xfv = 0.f;
      if (tid < 192){
        oldv = iou_acc[(size_t)pp*768 + (tid>>6)*TLH + ulo + (tid&63)];
      } else if (tid < 256){
        int fc = ulo + (tid-192);
        oldv = fcsum[(size_t)pp*256 + fc];
        xfv  = xf[(size_t)pp*256 + fc];
      }
      // matvec with h of previously-processed node
      float a = 0.f;
      #pragma unroll
      for (int r=0;r<16;r++){
        float4 h4 = *(const float4*)&hl[q*64 + r*4];
        a += h4.x*w4[r].x + h4.y*w4[r].y + h4.z*w4[r].z + h4.w*w4[r].w;
      }
      part[c][q] = a;
      __syncthreads();
      if (tid < 256){
        float v = part[tid][0] + part[tid][1] + part[tid][2] + part[tid][3];
        if (tid < 192){
          float tot = oldv + v;
          iou_acc[(size_t)pp*768 + (tid>>6)*TLH + ulo + (tid&63)] = tot;
          passv[tid] = tot;
        } else {
          float fg = sig_f(xfv + v);
          float tot = oldv + fg * cprev[tid-192];
          fcsum[(size_t)pp*256 + ulo + (tid-192)] = tot;
          passv[tid] = tot;
        }
      }
      __syncthreads();
    }
    // phase B: finish node n for our unit slice; publish h
    if (tid < 64){
      int u = ulo + tid;
      float ai, ao, au, fcs;
      if (ppeq){
        ai = passv[tid]; ao = passv[64+tid]; au = passv[128+tid]; fcs = passv[192+tid];
      } else {
        ai = iou_acc[(size_t)n*768 + u];
        ao = iou_acc[(size_t)n*768 + 256 + u];
        au = iou_acc[(size_t)n*768 + 512 + u];
        fcs = fcsum[(size_t)n*256 + u];
      }
      float cc = sig_f(xi + ai)*tanh_f(xu + au) + fcs;
      float hh = sig_f(xo + ao)*tanh_f(cc);
      cprev[tid] = cc;
      hl[u] = hh;
      __hip_atomic_store(&tree_h[(size_t)n*TLH + u], hh, __ATOMIC_RELAXED, __HIP_MEMORY_SCOPE_AGENT);
    }
    // gather foreign slices of node n via sentinel poll (data IS the flag)
    if (tid < 256 && (tid < ulo || tid >= uhi)){
      const unsigned* tp = (const unsigned*)(tree_h + (size_t)n*TLH + tid);
      unsigned v = __hip_atomic_load(tp, __ATOMIC_RELAXED, __HIP_MEMORY_SCOPE_AGENT);
      while (v == SENT){
        __builtin_amdgcn_s_sleep(1);
        v = __hip_atomic_load(tp, __ATOMIC_RELAXED, __HIP_MEMORY_SCOPE_AGENT);
      }
      hl[tid] = __uint_as_float(v);
    }
    __syncthreads();
  }
}

// ---------------- assemble SE + emissions + relations ----------------
__global__ __launch_bounds__(256) void k_assemble(
    const float* __restrict__ hf, const float* __restrict__ hb,
    const float* __restrict__ lcnn, const float* __restrict__ tree_h,
    const float* __restrict__ gcnn,
    const float* __restrict__ crf_w, const float* __restrict__ crf_b,
    const float* __restrict__ rel_w, const float* __restrict__ rel_b,
    const int* __restrict__ ptk,
    float* __restrict__ se_out, float* __restrict__ emis, float* __restrict__ rel_out)
{
  int s = blockIdx.x, tid = threadIdx.x;
  int p = ptk[0];
  __shared__ float se[1536];
  for (int d = tid; d < 1536; d += 256){
    float v;
    if      (d < 128)  v = hf[(size_t)s*128 + d];
    else if (d < 256)  v = hb[(size_t)s*128 + d-128];
    else if (d < 384)  v = lcnn[(size_t)s*128 + d-256];
    else if (d < 640)  v = tree_h[(size_t)s*256 + d-384];
    else if (d < 768)  v = hf[(size_t)p*128 + d-640];
    else if (d < 896)  v = hb[(size_t)p*128 + d-768];
    else if (d < 1024) v = lcnn[(size_t)p*128 + d-896];
    else if (d < 1280) v = tree_h[(size_t)p*256 + d-1024];
    else               v = gcnn[d-1280];
    se[d] = v;
    se_out[(size_t)s*1536 + d] = v;
  }
  __syncthreads();
  int o = tid >> 3, l = tid & 7;   // 32 outputs x 8 lanes
  const float* W = (o < 16) ? crf_w : rel_w;
  int oc = (o < 16) ? o : (o - 16);
  float a = 0.f;
  for (int k = l; k < 1536; k += 8) a += se[k]*W[(size_t)k*16 + oc];
  for (int off = 4; off; off >>= 1) a += __shfl_down(a, off, 8);
  if (l == 0){
    if (o < 16) emis[(size_t)s*16 + o] = a + crf_b[o];
    else        rel_out[(size_t)s*16 + oc] = sig_f(a + rel_b[oc]);
  }
}

// ---------------- entity type ----------------
__global__ __launch_bounds__(256) void k_entity(
    const float* __restrict__ hf, const float* __restrict__ hb,
    const float* __restrict__ lcnn, const float* __restrict__ tree_h,
    const float* __restrict__ gcnn,
    const float* __restrict__ et_w, const float* __restrict__ et_b,
    const int* __restrict__ ptk, float* __restrict__ out_et)
{
  __shared__ float ov[896];
  __shared__ float lg[8];
  int tid = threadIdx.x;
  int p = ptk[0];
  for (int d = tid; d < 896; d += 256){
    float v;
    if      (d < 256) v = gcnn[d];
    else if (d < 384) v = hf[(size_t)p*128 + d-256];
    else if (d < 512) v = hb[(size_t)p*128 + d-384];
    else if (d < 640) v = lcnn[(size_t)p*128 + d-512];
    else              v = tree_h[(size_t)p*256 + d-640];
    ov[d] = v;
  }
  __syncthreads();
  int o = tid >> 5, l = tid & 31;
  float a = 0.f;
  for (int k = l; k < 896; k += 32) a += ov[k]*et_w[(size_t)k*8 + o];
  for (int off = 16; off; off >>= 1) a += __shfl_down(a, off, 32);
  if (l == 0) lg[o] = a + et_b[o];
  __syncthreads();
  if (tid == 0){
    float mx = lg[0];
    for (int i=1;i<8;i++) mx = fmaxf(mx, lg[i]);
    float e[8], sum = 0.f;
    for (int i=0;i<8;i++){ e[i] = __expf(lg[i]-mx); sum += e[i]; }
    for (int i=0;i<8;i++) out_et[i] = e[i]/sum;
  }
}

// ---------------- viterbi ----------------
__global__ __launch_bounds__(128) void k_viterbi(
    const float* __restrict__ emis, const float* __restrict__ trans, float* __restrict__ out_e)
{
  __shared__ float ring[64][16];
  __shared__ float sc[16], nsc[16];
  __shared__ float tr[256];
  __shared__ unsigned char ptrs[1023*16];
  int tid = threadIdx.x;
  for (int i=tid; i<256; i+=128) tr[i] = trans[i];
  for (int i=tid; i<33*16; i+=128) ring[i>>4][i&15] = emis[i];   // rows 0..32
  if (tid < 16) sc[tid] = emis[tid];
  __syncthreads();
  int j = (tid & 63) >> 2, iq = tid & 3;
  for (int t=1; t<1024; t++){
    if (tid >= 64){
      int lr = tid - 64;
      int tl = t + 32;
      if (lr < 16 && tl < 1024) ring[tl & 63][lr] = emis[(size_t)tl*16 + lr];
    } else {
      float best = -3.0e38f; int barg = 0;
      #pragma unroll
      for (int ii=0; ii<4; ii++){
        int i = iq*4 + ii;
        float v = sc[i] + tr[i*16 + j];
        if (v > best){ best = v; barg = i; }   // strict > keeps first max
      }
      #pragma unroll
      for (int off=1; off<4; off<<=1){
        float ovv = __shfl_down(best, off, 4);
        int   oaa = __shfl_down(barg, off, 4);
        if (ovv > best){ best = ovv; barg = oaa; }
      }
      if (iq == 0){
        nsc[j] = best + ring[t & 63][j];
        ptrs[(t-1)*16 + j] = (unsigned char)barg;
      }
    }
    __syncthreads();
    if (tid < 16) sc[tid] = nsc[tid];
    __syncthreads();
  }
  if (tid == 0){
    float b = sc[0]; int last = 0;
    #pragma unroll
    for (int i=1;i<16;i++){ if (sc[i] > b){ b = sc[i]; last = i; } }
    out_e[1023] = (float)last;
    int cur = last;
    for (int t=1022; t>=0; t--){ cur = (int)ptrs[t*16 + cur]; out_e[t] = (float)cur; }
  }
}

extern "C" void kernel_launch(void* const* d_in, const int* in_sizes, int n_in,
                              void* d_out, int out_size, void* d_ws, size_t ws_size,
                              hipStream_t stream)
{
  (void)in_sizes; (void)n_in; (void)out_size; (void)ws_size;
  const int*   wi         = (const int*)d_in[0];
  const int*   ci         = (const int*)d_in[1];
  const int*   postag_in  = (const int*)d_in[2];
  const int*   dep_in     = (const int*)d_in[3];
  const int*   pos_in     = (const int*)d_in[4];
  const int*   order      = (const int*)d_in[5];
  const int*   parent     = (const int*)d_in[6];
  const int*   ptk        = (const int*)d_in[7];
  const float* word_table = (const float*)d_in[8];
  const float* char_table = (const float*)d_in[9];
  const float* ccw        = (const float*)d_in[10];
  const float* ccb        = (const float*)d_in[11];
  const float* postag_tab = (const float*)d_in[12];
  const float* pos_tab    = (const float*)d_in[13];
  const float* Wx_f       = (const float*)d_in[14];
  const float* Wh_f       = (const float*)d_in[15];
  const float* b_f        = (const float*)d_in[16];
  const float* Wx_b       = (const float*)d_in[17];
  const float* Wh_b       = (const float*)d_in[18];
  const float* b_b        = (const float*)d_in[19];
  const float* wcnn_w     = (const float*)d_in[20];
  const float* wcnn_b     = (const float*)d_in[21];
  const float* Wiou       = (const float*)d_in[22];
  const float* Uiou       = (const float*)d_in[23];
  const float* biou       = (const float*)d_in[24];
  const float* Wf_t       = (const float*)d_in[25];
  const float* Uf_t       = (const float*)d_in[26];
  const float* bf_t       = (const float*)d_in[27];
  const float* scnn_w     = (const float*)d_in[28];
  const float* scnn_b     = (const float*)d_in[29];
  const float* et_w       = (const float*)d_in[30];
  const float* et_b       = (const float*)d_in[31];
  const float* crf_w      = (const float*)d_in[32];
  const float* crf_b      = (const float*)d_in[33];
  const float* crf_trans  = (const float*)d_in[34];
  const float* rel_w      = (const float*)d_in[35];
  const float* rel_b      = (const float*)d_in[36];

  float* ws = (float*)d_ws;
  float* x      = ws + O_X;
  float* xg_f   = ws + O_XGF;
  float* xg_b   = ws + O_XGB;
  float* xiou   = ws + O_XIOU;
  float* xf     = ws + O_XF;
  float* lcnn   = ws + O_LCNN;
  float* scnn   = ws + O_SCNN;
  float* gcnn   = ws + O_GCNN;
  float* hf     = ws + O_HF;
  float* hb     = ws + O_HB;
  float* tree_h = ws + O_TREEH;
  float* iou_acc= ws + O_IOUA;
  float* fcsum  = ws + O_FCSUM;
  float* emis   = ws + O_EMIS;

  float* outF     = (float*)d_out;
  float* se_out   = outF;                       // 1024*1536
  float* et_out   = outF + 1572864;             // 8
  float* ent_out  = outF + 1572872;             // 1024
  float* rel_out  = outF + 1573896;             // 1024*16

  // per-launch init: zero accumulators + xf pad row; sentinel-fill tree_h
  hipMemsetAsync(xf, 0, (size_t)1025*256*sizeof(float), stream);
  hipMemsetAsync(iou_acc, 0, ((size_t)1025*768 + 1025*256)*sizeof(float), stream);
  hipMemsetAsync(tree_h, 0xFF, (size_t)1024*256*sizeof(float), stream);

  k_embed<<<SEQ, 128, 0, stream>>>(wi, ci, postag_in, dep_in, pos_in,
                                   word_table, char_table, ccw, ccb,
                                   postag_tab, pos_tab, x);

  GemmArgs ga;
  ga.B[0]=Wx_f;  ga.bias[0]=b_f;   ga.C[0]=xg_f; ga.N[0]=512; ga.K[0]=620;  ga.amode[0]=0;
  ga.B[1]=Wx_b;  ga.bias[1]=b_b;   ga.C[1]=xg_b; ga.N[1]=512; ga.K[1]=620;  ga.amode[1]=0;
  ga.B[2]=Wiou;  ga.bias[2]=biou;  ga.C[2]=xiou; ga.N[2]=768; ga.K[2]=620;  ga.amode[2]=0;
  ga.B[3]=Wf_t;  ga.bias[3]=bf_t;  ga.C[3]=xf;   ga.N[3]=256; ga.K[3]=620;  ga.amode[3]=0;
  ga.B[4]=wcnn_w;ga.bias[4]=wcnn_b;ga.C[4]=lcnn; ga.N[4]=128; ga.K[4]=1860; ga.amode[4]=1;
  ga.B[5]=scnn_w;ga.bias[5]=scnn_b;ga.C[5]=scnn; ga.N[5]=256; ga.K[5]=1860; ga.amode[5]=1;
  k_gemm<<<dim3(12,16,6), 256, 0, stream>>>(x, ga);

  k_gmax<<<1, 256, 0, stream>>>(scnn, gcnn);

  k_recur<<<6, 1024, 0, stream>>>(xg_f, xg_b, Wh_f, Wh_b, xiou, xf, Uiou, Uf_t,
                                  order, parent, hf, hb, tree_h, iou_acc, fcsum);

  k_assemble<<<SEQ, 256, 0, stream>>>(hf, hb, lcnn, tree_h, gcnn,
                                      crf_w, crf_b, rel_w, rel_b, ptk,
                                      se_out, emis, rel_out);

  k_entity<<<1, 256, 0, stream>>>(hf, hb, lcnn, tree_h, gcnn, et_w, et_b, ptk, et_out);

  k_viterbi<<<1, 128, 0, stream>>>(emis, crf_trans, ent_out);
}